// Round 11
// baseline (143.099 us; speedup 1.0000x reference)
//
#include <hip/hip_runtime.h>

#define HH 128
#define WW 128
#define CC 64
#define IMG (HH*WW*CC)

// tile: 8 rows x 4 cols = 32 px/block, 1 px per thread (8 lanes x 8 ch)
// halo: 12 rows x 8 cols = 96 positions
// LDS:  [pos(96)][mat(2)][slot(8)] uint4 (8 bf16 ch each) = 24576 B -> 6 blk/CU

__device__ __forceinline__ unsigned pack2bf(float a, float b){
  unsigned ua = __float_as_uint(a), ub = __float_as_uint(b);
  ua = (ua + 0x7fffu + ((ua>>16)&1u)) >> 16;            // RTN
  ub = (ub + 0x7fffu + ((ub>>16)&1u)) >> 16;
  return ua | (ub<<16);
}

__device__ __forceinline__ float bflo(unsigned u){ return __uint_as_float(u<<16); }
__device__ __forceinline__ float bfhi(unsigned u){ return __uint_as_float(u & 0xffff0000u); }

template<int CTRL>
__device__ __forceinline__ float dpp_addstep(float x){
  int p = __builtin_amdgcn_update_dpp(0, __float_as_int(x), CTRL, 0xf, 0xf, true);
  return x + __int_as_float(p);
}
// sum across 8 consecutive lanes (groups aligned to lane&~7) — pure VALU/DPP
__device__ __forceinline__ float reduce8(float x){
  x = dpp_addstep<0xB1>(x);    // xor 1
  x = dpp_addstep<0x4E>(x);    // xor 2
  x = dpp_addstep<0x141>(x);   // row_half_mirror
  return x;
}

__global__ __launch_bounds__(256, 4) void local_attn_kernel(
    const float* __restrict__ main_,
    const float* __restrict__ main_value,
    const float* __restrict__ ref,
    const float* __restrict__ ref_value,
    float* __restrict__ out)
{
    __shared__ uint4 kv4[96*2*8];   // 24576 B

    const int t   = threadIdx.x;
    // XCD swizzle: 2048 % 8 == 0 -> bijective
    const int blk = (blockIdx.x & 7) * 256 + (blockIdx.x >> 3);
    const int b    = blk >> 9;          // image
    const int tile = blk & 511;
    const int ty   = tile >> 5;         // 0..15, 8 rows each
    const int tx   = tile & 31;         // 0..31, 4 cols each

    const int y0 = ty*8 - 2, x0 = tx*4 - 2;
    const size_t img = (size_t)b * IMG;

    // ---- staging descriptors: slot/mat are per-thread CONSTANT, pos += 16/unit
    const int slot = t & 7;
    const int mat  = (t >> 3) & 1;
    const int pos0 = t >> 4;            // unit u covers pos0 + 16u
    const float* src = (mat ? ref_value : ref) + img;

    // ---- fenced staging: 3 groups of 2 units; fence stops load-hoisting ----
    #define STAGE_UNIT(u) {                                                    \
        const int pos = pos0 + ((u)<<4);                                       \
        const int hy = pos >> 3, hx = pos & 7;                                 \
        const int yy = y0 + hy, xx = x0 + hx;                                  \
        float4 A = make_float4(0.f,0.f,0.f,0.f);                               \
        float4 C = make_float4(0.f,0.f,0.f,0.f);                               \
        if ((unsigned)yy < HH && (unsigned)xx < WW) {                          \
            const float* g = src + ((size_t)yy*WW + xx)*CC + slot*8;           \
            A = ((const float4*)g)[0];                                         \
            C = ((const float4*)g)[1];                                         \
        }                                                                      \
        kv4[pos*16 + mat*8 + (slot ^ (pos & 7))] =                             \
            make_uint4(pack2bf(A.x,A.y), pack2bf(A.z,A.w),                     \
                       pack2bf(C.x,C.y), pack2bf(C.z,C.w));                    \
    }

    STAGE_UNIT(0); STAGE_UNIT(1);
    asm volatile("" ::: "memory");
    STAGE_UNIT(2); STAGE_UNIT(3);
    asm volatile("" ::: "memory");
    STAGE_UNIT(4); STAGE_UNIT(5);

    __syncthreads();    // the ONLY barrier

    // ---- per-pixel setup (after barrier: none of this is live in staging) ----
    const int cg8 = t & 7;
    const int px  = t >> 3;
    const int lx  = px & 3;
    const int ly  = px >> 2;
    const size_t off = img + ((size_t)(ty*8+ly)*WW + (tx*4+lx))*CC + cg8*8;

    float4 qv0 = *(const float4*)(main_+off);
    float4 qv1 = *(const float4*)(main_+off+4);
    float q[8] = {qv0.x,qv0.y,qv0.z,qv0.w,qv1.x,qv1.y,qv1.z,qv1.w};

    // per-pixel softmax shift = self logit |q|^2 (exact, overflow-safe)
    float lq;
    {
        float a = 0.f;
        #pragma unroll
        for (int c = 0; c < 8; ++c) a = fmaf(q[c],q[c],a);
        lq = reduce8(a);
    }

    float o[8];
    #pragma unroll
    for (int c = 0; c < 8; ++c) o[c] = 0.f;
    float s = 0.f;

    // ---- 25 window positions, unpack fused into FMAs ----
    #pragma unroll
    for (int di = 0; di < 5; ++di) {
        #pragma unroll
        for (int dj = 0; dj < 5; ++dj) {
            const int pos = (ly+di)*8 + (lx+dj);
            const int sw  = cg8 ^ (pos & 7);
            const uint4 kk = kv4[pos*16 + sw];
            const uint4 vv = kv4[pos*16 + 8 + sw];
            float l = 0.f;
            l = fmaf(q[0], bflo(kk.x), l); l = fmaf(q[1], bfhi(kk.x), l);
            l = fmaf(q[2], bflo(kk.y), l); l = fmaf(q[3], bfhi(kk.y), l);
            l = fmaf(q[4], bflo(kk.z), l); l = fmaf(q[5], bfhi(kk.z), l);
            l = fmaf(q[6], bflo(kk.w), l); l = fmaf(q[7], bfhi(kk.w), l);
            l = reduce8(l);
            const float w = __expf(l - lq);     // arg bounded, no overflow
            s += w;
            o[0] = fmaf(w, bflo(vv.x), o[0]); o[1] = fmaf(w, bfhi(vv.x), o[1]);
            o[2] = fmaf(w, bflo(vv.y), o[2]); o[3] = fmaf(w, bfhi(vv.y), o[3]);
            o[4] = fmaf(w, bflo(vv.z), o[4]); o[5] = fmaf(w, bfhi(vv.z), o[5]);
            o[6] = fmaf(w, bflo(vv.w), o[6]); o[7] = fmaf(w, bfhi(vv.w), o[7]);
        }
    }

    // ---- self slot (weight exactly 1), value loaded only now ----
    {
        float4 mv0 = *(const float4*)(main_value+off);
        float4 mv1 = *(const float4*)(main_value+off+4);
        s += 1.f;
        o[0] += mv0.x; o[1] += mv0.y; o[2] += mv0.z; o[3] += mv0.w;
        o[4] += mv1.x; o[5] += mv1.y; o[6] += mv1.z; o[7] += mv1.w;
    }

    const float rs = 1.f/s;
    float4 r;
    r.x=o[0]*rs; r.y=o[1]*rs; r.z=o[2]*rs; r.w=o[3]*rs;
    *(float4*)(out+off) = r;
    r.x=o[4]*rs; r.y=o[5]*rs; r.z=o[6]*rs; r.w=o[7]*rs;
    *(float4*)(out+off+4) = r;
}

extern "C" void kernel_launch(void* const* d_in, const int* in_sizes, int n_in,
                              void* d_out, int out_size, void* d_ws, size_t ws_size,
                              hipStream_t stream) {
    const float* main_      = (const float*)d_in[0];
    const float* main_value = (const float*)d_in[1];
    const float* ref        = (const float*)d_in[2];
    const float* ref_value  = (const float*)d_in[3];
    float* out = (float*)d_out;

    // 4 images x 16 y-tiles x 32 x-tiles = 2048 blocks
    local_attn_kernel<<<dim3(2048), dim3(256), 0, stream>>>(
        main_, main_value, ref, ref_value, out);
}